// Round 2
// baseline (531.852 us; speedup 1.0000x reference)
//
#include <hip/hip_runtime.h>
#include <hip/hip_bf16.h>
#include <cfloat>
#include <math.h>

// Problem: B=4,T=32,N=96,K=30, NUM_HIDDEN=128, NUM_IN=256, H=4, d=32
constexpr int SITES = 12288;
constexpr int KNB   = 30;
constexpr int CIN   = 256;
#define RSQRT_D 0.17677669529663689f

typedef short bf16x8 __attribute__((ext_vector_type(8)));   // 8 bf16 in 4 VGPRs
typedef float f32x4  __attribute__((ext_vector_type(4)));

__device__ inline unsigned short f2bs(float x) {
    __hip_bfloat16 b = __float2bfloat16(x);            // RTN-even
    return *(unsigned short*)&b;
}
__device__ inline float bs2f(unsigned short u) {
    unsigned int v = (unsigned int)u << 16;
    float f;
    __builtin_memcpy(&f, &v, 4);
    return f;
}
__device__ inline unsigned int pack2(float a, float b) {
    return (unsigned int)f2bs(a) | ((unsigned int)f2bs(b) << 16);
}

// ---------------------------------------------------------------------------
// Weight precompute (bf16, transposed for B^T GEMM) + out zero-fill.
//   Mt[(h*256+c)*128 + i] = sum_d Wq[i][h*32+d] * Wk[c][h*32+d]   (1024 x 128)
//   W3t[j*1024 + h*256+c] = sum_d Wv[c][h*32+d] * Wo[h*32+d][j]   (128 x 1024)
// Blocks >= 1024 zero `out` (12288x128 f32) so GEMM2 can atomicAdd K-slices.
// ---------------------------------------------------------------------------
__global__ __launch_bounds__(256) void precompute_w(
    const float* __restrict__ Wq, const float* __restrict__ Wk,
    const float* __restrict__ Wv, const float* __restrict__ Wo,
    unsigned short* __restrict__ Mt, unsigned short* __restrict__ W3t,
    float* __restrict__ outZ) {
    if (blockIdx.x >= 1024) {                     // 384 blocks: zero out
        int idx = (blockIdx.x - 1024) * 256 + threadIdx.x;   // 0..98303
        float4 z = {0.f, 0.f, 0.f, 0.f};
        float4* o4 = (float4*)outZ;
        #pragma unroll
        for (int j = 0; j < 4; ++j) o4[(size_t)j * 98304 + idx] = z;
        return;
    }
    int gid = blockIdx.x * 256 + threadIdx.x;
    if (gid < 131072) {
        int p = gid >> 7;          // h*256+c
        int i = gid & 127;
        int h = p >> 8;
        int c = p & 255;
        const float4* wq = (const float4*)(Wq + (size_t)i * 128 + h * 32);
        const float4* wk = (const float4*)(Wk + (size_t)c * 128 + h * 32);
        float s = 0.f;
        #pragma unroll
        for (int d = 0; d < 8; ++d) {
            float4 a = wq[d], b = wk[d];
            s += a.x * b.x; s += a.y * b.y; s += a.z * b.z; s += a.w * b.w;
        }
        Mt[gid] = f2bs(s);
    } else {
        int o = gid - 131072;
        int p = o >> 7;            // h*256+c  (wave-uniform)
        int j = o & 127;           // lanes vary j -> coalesced Wo
        int h = p >> 8;
        int c = p & 255;
        const float* wv = Wv + (size_t)c * 128 + h * 32;
        const float* wo = Wo + (size_t)(h * 32) * 128 + j;
        float s = 0.f;
        #pragma unroll
        for (int d = 0; d < 32; ++d)
            s += wv[d] * wo[(size_t)d * 128];
        W3t[(size_t)j * 1024 + p] = f2bs(s);
    }
}

// ---------------------------------------------------------------------------
// bf16 MFMA GEMM, B^T input:  C(MxN) = A(MxK) @ Bt(NxK)^T
// block = 256 thr (4 waves), BM=64 (16 rows/wave), BN template, BK=32.
// 2-stage register prefetch: next tile's global loads issue right after the
// first barrier, overlapping MFMA compute (kills exposed per-K-step latency).
// A_F32: A is fp32, converted to bf16 during staging.
// ATOMIC: fp32 atomicAdd epilogue (K-split; out must be pre-zeroed).
// blockIdx.z selects a Kc-sized K-chunk.
// ---------------------------------------------------------------------------
template <int BN, bool OUT_BF16, bool A_F32, bool ATOMIC>
__global__ __launch_bounds__(256) void gemm_bt_bf16(
    const void* __restrict__ Aptr, const unsigned short* __restrict__ Bt,
    void* __restrict__ C, int M, int N, int K, int Kc) {
    constexpr int BM = 64, BK = 32, PAD = 8;
    constexpr int NT  = BN / 16;                  // n-tiles per wave
    constexpr int BCH = (BN * BK) / (8 * 256);    // B uint4 chunks per thread
    __shared__ unsigned short As[BM][BK + PAD];
    __shared__ unsigned short Bs[BN][BK + PAD];
    const int tid  = threadIdx.x;
    const int wave = tid >> 6;
    const int lane = tid & 63;
    const int quad = lane >> 4;
    const int l16  = lane & 15;
    const int bm0 = blockIdx.x * BM;
    const int bn0 = blockIdx.y * BN;
    const int k0  = blockIdx.z * Kc;
    const int arow = tid >> 2, aoff = (tid & 3) * 8;

    f32x4 acc[NT];
    #pragma unroll
    for (int j = 0; j < NT; ++j) acc[j] = (f32x4){0.f, 0.f, 0.f, 0.f};

    const float* Af = (const float*)Aptr;
    const unsigned short* Ab = (const unsigned short*)Aptr;

    float4 af0, af1; uint4 apre; uint4 bpre[BCH];
    {   // prologue: prefetch first tile into registers
        if (A_F32) {
            const float4* src = (const float4*)&Af[(size_t)(bm0 + arow) * K + k0 + aoff];
            af0 = src[0]; af1 = src[1];
        } else {
            apre = *(const uint4*)&Ab[(size_t)(bm0 + arow) * K + k0 + aoff];
        }
        #pragma unroll
        for (int i = 0; i < BCH; ++i) {
            int c2 = i * 256 + tid;
            bpre[i] = *(const uint4*)&Bt[(size_t)(bn0 + (c2 >> 2)) * K + k0 + (c2 & 3) * 8];
        }
    }
    for (int kk = k0; kk < k0 + Kc; kk += BK) {
        // drain staged registers -> LDS
        if (A_F32) {
            uint4 p;
            p.x = pack2(af0.x, af0.y); p.y = pack2(af0.z, af0.w);
            p.z = pack2(af1.x, af1.y); p.w = pack2(af1.z, af1.w);
            *(uint4*)&As[arow][aoff] = p;
        } else {
            *(uint4*)&As[arow][aoff] = apre;
        }
        #pragma unroll
        for (int i = 0; i < BCH; ++i) {
            int c2 = i * 256 + tid;
            *(uint4*)&Bs[c2 >> 2][(c2 & 3) * 8] = bpre[i];
        }
        __syncthreads();
        // prefetch next tile (overlaps with MFMA below)
        int kn = kk + BK;
        if (kn < k0 + Kc) {
            if (A_F32) {
                const float4* src = (const float4*)&Af[(size_t)(bm0 + arow) * K + kn + aoff];
                af0 = src[0]; af1 = src[1];
            } else {
                apre = *(const uint4*)&Ab[(size_t)(bm0 + arow) * K + kn + aoff];
            }
            #pragma unroll
            for (int i = 0; i < BCH; ++i) {
                int c2 = i * 256 + tid;
                bpre[i] = *(const uint4*)&Bt[(size_t)(bn0 + (c2 >> 2)) * K + kn + (c2 & 3) * 8];
            }
        }
        bf16x8 afr = *(const bf16x8*)&As[wave * 16 + l16][quad * 8];
        #pragma unroll
        for (int j = 0; j < NT; ++j) {
            bf16x8 bfr = *(const bf16x8*)&Bs[j * 16 + l16][quad * 8];
            acc[j] = __builtin_amdgcn_mfma_f32_16x16x32_bf16(afr, bfr, acc[j], 0, 0, 0);
        }
        __syncthreads();
    }
    // C/D layout: col = lane&15, row = quad*4 + reg  (m89-verified)
    int row0 = bm0 + wave * 16 + quad * 4;
    #pragma unroll
    for (int j = 0; j < NT; ++j) {
        int col = bn0 + j * 16 + l16;
        #pragma unroll
        for (int r = 0; r < 4; ++r) {
            size_t idx = (size_t)(row0 + r) * N + col;
            if (ATOMIC)
                unsafeAtomicAdd(&((float*)C)[idx], acc[j][r]);
            else if (OUT_BF16)
                ((unsigned short*)C)[idx] = f2bs(acc[j][r]);
            else
                ((float*)C)[idx] = acc[j][r];
        }
    }
}

// ---------------------------------------------------------------------------
// Fused masked neighbor attention. One block (4 waves) per site.
//  Phase 0 : wave0 builds active-row list; waves1-2 stage q~ to LDS as f32.
//  Phase 1 : half-wave per row; ALL owned rows' hEV loads issue back-to-back
//            (static 4-slot prefetch) before compute -> one exposed latency.
//  Phase 2 : softmax per head (wave h).
//  Phase 3 : evbar accum from LDS (thread = column), bf16 output.
// ---------------------------------------------------------------------------
__global__ __launch_bounds__(256) void attn_kernel(
    const float* __restrict__ hEV, const int* __restrict__ mask,
    const unsigned short* __restrict__ qt, unsigned short* __restrict__ evb) {
    __shared__ unsigned short evS[KNB * CIN];   // 15 KB (bf16)
    __shared__ float qS[1024];                  // 4 KB (q~ as f32)
    __shared__ float logitsL[4 * 32];
    __shared__ float attendL[4 * 32];
    __shared__ int   activeS[32];
    __shared__ int   naS;

    const int s = blockIdx.x;
    const int tid = threadIdx.x;
    const int lane = tid & 63;
    const int wv = tid >> 6;
    const int hw = lane >> 5;        // half-wave id
    const int sl = lane & 31;        // lane within half

    // --- phase 0: active list (wave 0) + q~ staging (waves 1-2) ---
    if (tid < 64) {
        int mk = (tid < KNB) ? mask[(size_t)s * KNB + tid] : 0;
        unsigned long long bal = __ballot(mk > 0);
        if (tid == 0) naS = __popcll(bal);
        if (mk > 0) activeS[__popcll(bal & ((1ull << tid) - 1))] = tid;
    } else if (tid < 192) {
        int t2 = tid - 64;           // 0..127, one uint4 (8 bf16) each
        uint4 u = ((const uint4*)(qt + (size_t)s * 1024))[t2];
        float f[8];
        f[0] = bs2f(u.x & 0xffff); f[1] = bs2f(u.x >> 16);
        f[2] = bs2f(u.y & 0xffff); f[3] = bs2f(u.y >> 16);
        f[4] = bs2f(u.z & 0xffff); f[5] = bs2f(u.z >> 16);
        f[6] = bs2f(u.w & 0xffff); f[7] = bs2f(u.w >> 16);
        *(float4*)&qS[t2 * 8]     = *(float4*)&f[0];
        *(float4*)&qS[t2 * 8 + 4] = *(float4*)&f[4];
    }
    __syncthreads();

    // --- per-lane q fragment: channels sl*8 .. sl*8+7, all 4 heads ---
    float qf[4][8];
    #pragma unroll
    for (int h = 0; h < 4; ++h) {
        *(float4*)&qf[h][0] = *(const float4*)&qS[h * 256 + sl * 8];
        *(float4*)&qf[h][4] = *(const float4*)&qS[h * 256 + sl * 8 + 4];
    }
    const int na = naS;

    // --- phase 1: batch-issue all owned rows (<=4), then compute ---
    const float* base = hEV + (size_t)s * (KNB * CIN) + sl * 8;
    float4 va[4], vb[4];
    int rw[4];
    #pragma unroll
    for (int i = 0; i < 4; ++i) {
        int r = wv * 2 + hw + i * 8;
        rw[i] = (r < na) ? r : -1;
        if (r < na) {
            const float* row = base + (size_t)activeS[r] * CIN;
            va[i] = *(const float4*)row;
            vb[i] = *(const float4*)(row + 4);
        }
    }
    #pragma unroll
    for (int i = 0; i < 4; ++i) {
        if (rw[i] >= 0) {
            int r = rw[i];
            float4 v0 = va[i], v1 = vb[i];
            uint4 p;
            p.x = pack2(v0.x, v0.y); p.y = pack2(v0.z, v0.w);
            p.z = pack2(v1.x, v1.y); p.w = pack2(v1.z, v1.w);
            *(uint4*)&evS[r * CIN + sl * 8] = p;

            float l[4];
            #pragma unroll
            for (int h = 0; h < 4; ++h) {
                l[h] = v0.x * qf[h][0] + v0.y * qf[h][1] + v0.z * qf[h][2] + v0.w * qf[h][3]
                     + v1.x * qf[h][4] + v1.y * qf[h][5] + v1.z * qf[h][6] + v1.w * qf[h][7];
            }
            #pragma unroll
            for (int m = 1; m < 32; m <<= 1) {
                #pragma unroll
                for (int h = 0; h < 4; ++h) l[h] += __shfl_xor(l[h], m, 64);
            }
            if (sl == 0) {
                #pragma unroll
                for (int h = 0; h < 4; ++h) logitsL[h * 32 + r] = l[h] * RSQRT_D;
            }
        }
    }
    __syncthreads();

    // --- phase 2: softmax over active slots: wave h ---
    {
        float lg = (lane < na) ? logitsL[wv * 32 + lane] : -FLT_MAX;
        float mx = lg;
        #pragma unroll
        for (int m = 1; m < 64; m <<= 1) mx = fmaxf(mx, __shfl_xor(mx, m, 64));
        float e = (lane < na) ? __expf(lg - mx) : 0.f;
        float sm = e;
        #pragma unroll
        for (int m = 1; m < 64; m <<= 1) sm += __shfl_xor(sm, m, 64);
        if (lane < na) attendL[wv * 32 + lane] = e / sm;
    }
    __syncthreads();

    // --- phase 3: evbar, thread t owns column c = t ---
    float a0 = 0.f, a1 = 0.f, a2 = 0.f, a3 = 0.f;
    for (int r = 0; r < na; ++r) {
        float evv = bs2f(evS[r * CIN + tid]);
        a0 = fmaf(attendL[r], evv, a0);
        a1 = fmaf(attendL[32 + r], evv, a1);
        a2 = fmaf(attendL[64 + r], evv, a2);
        a3 = fmaf(attendL[96 + r], evv, a3);
    }
    size_t ob = (size_t)s * 1024 + tid;
    evb[ob]       = f2bs(a0);
    evb[ob + 256] = f2bs(a1);
    evb[ob + 512] = f2bs(a2);
    evb[ob + 768] = f2bs(a3);
}

// ---------------------------------------------------------------------------
extern "C" void kernel_launch(void* const* d_in, const int* in_sizes, int n_in,
                              void* d_out, int out_size, void* d_ws, size_t ws_size,
                              hipStream_t stream) {
    const float* hV   = (const float*)d_in[0];
    const float* hEV  = (const float*)d_in[1];
    const int*   mask = (const int*)d_in[2];
    const float* Wq   = (const float*)d_in[3];
    const float* Wk   = (const float*)d_in[4];
    const float* Wv   = (const float*)d_in[5];
    const float* Wo   = (const float*)d_in[6];
    float* out = (float*)d_out;

    unsigned short* ws = (unsigned short*)d_ws;   // element = 2 B
    unsigned short* Mt   = ws;                            // 1024*128
    unsigned short* W3t  = ws + 131072;                   // 128*1024
    unsigned short* qt   = ws + 262144;                   // 12288*1024
    unsigned short* evb  = qt + (size_t)SITES * 1024;     // 12288*1024
    size_t need = ((size_t)262144 + 2 * (size_t)SITES * 1024) * 2;
    if (ws_size < need) return;

    // weights + zero(out) fused in one dispatch
    precompute_w<<<dim3(1408), dim3(256), 0, stream>>>(Wq, Wk, Wv, Wo, Mt, W3t, out);

    // qt (12288x1024, bf16) = bf16(hV) (12288x128) @ Mt^T  (BN=256, prefetch)
    gemm_bt_bf16<256, true, true, false>
        <<<dim3(SITES / 64, 1024 / 256, 1), dim3(256), 0, stream>>>(
            hV, Mt, qt, SITES, 1024, 128, 128);

    // fused masked attention -> evb (12288x1024, bf16)
    attn_kernel<<<dim3(SITES), dim3(256), 0, stream>>>(hEV, mask, qt, evb);

    // out (12288x128, fp32) += evb @ W3t^T  (K split x4, atomic epilogue)
    gemm_bt_bf16<128, false, false, true>
        <<<dim3(SITES / 64, 1, 4), dim3(256), 0, stream>>>(
            evb, W3t, out, SITES, 128, 1024, 256);
}

// Round 3
// 523.964 us; speedup vs baseline: 1.0151x; 1.0151x over previous
//
#include <hip/hip_runtime.h>
#include <hip/hip_bf16.h>
#include <cfloat>
#include <math.h>

// Problem: B=4,T=32,N=96,K=30, NUM_HIDDEN=128, NUM_IN=256, H=4, d=32
constexpr int SITES = 12288;
constexpr int KNB   = 30;
constexpr int CIN   = 256;
#define RSQRT_D 0.17677669529663689f

typedef short bf16x8 __attribute__((ext_vector_type(8)));   // 8 bf16 in 4 VGPRs
typedef float f32x4  __attribute__((ext_vector_type(4)));

__device__ inline unsigned short f2bs(float x) {
    __hip_bfloat16 b = __float2bfloat16(x);            // RTN-even
    return *(unsigned short*)&b;
}
__device__ inline float bs2f(unsigned short u) {
    unsigned int v = (unsigned int)u << 16;
    float f;
    __builtin_memcpy(&f, &v, 4);
    return f;
}
__device__ inline unsigned int pack2(float a, float b) {
    return (unsigned int)f2bs(a) | ((unsigned int)f2bs(b) << 16);
}

// ---------------------------------------------------------------------------
// Weight precompute (bf16, transposed for B^T GEMM):
//   Mt[(h*256+c)*128 + i] = sum_d Wq[i][h*32+d] * Wk[c][h*32+d]   (1024 x 128)
//   W3t[j*1024 + h*256+c] = sum_d Wv[c][h*32+d] * Wo[h*32+d][j]   (128 x 1024)
// ---------------------------------------------------------------------------
__global__ __launch_bounds__(256) void precompute_w(
    const float* __restrict__ Wq, const float* __restrict__ Wk,
    const float* __restrict__ Wv, const float* __restrict__ Wo,
    unsigned short* __restrict__ Mt, unsigned short* __restrict__ W3t) {
    int gid = blockIdx.x * 256 + threadIdx.x;
    if (gid < 131072) {
        int p = gid >> 7;          // h*256+c
        int i = gid & 127;
        int h = p >> 8;
        int c = p & 255;
        const float4* wq = (const float4*)(Wq + (size_t)i * 128 + h * 32);
        const float4* wk = (const float4*)(Wk + (size_t)c * 128 + h * 32);
        float s = 0.f;
        #pragma unroll
        for (int d = 0; d < 8; ++d) {
            float4 a = wq[d], b = wk[d];
            s += a.x * b.x; s += a.y * b.y; s += a.z * b.z; s += a.w * b.w;
        }
        Mt[gid] = f2bs(s);
    } else {
        int o = gid - 131072;
        int p = o >> 7;            // h*256+c  (wave-uniform)
        int j = o & 127;           // lanes vary j -> coalesced Wo
        int h = p >> 8;
        int c = p & 255;
        const float* wv = Wv + (size_t)c * 128 + h * 32;
        const float* wo = Wo + (size_t)(h * 32) * 128 + j;
        float s = 0.f;
        #pragma unroll
        for (int d = 0; d < 32; ++d)
            s += wv[d] * wo[(size_t)d * 128];
        W3t[(size_t)j * 1024 + p] = f2bs(s);
    }
}

// ---------------------------------------------------------------------------
// bf16 MFMA GEMM, B^T input:  C(MxN) = A(MxK) @ Bt(NxK)^T   (round-1 form)
// block = 256 thr (4 waves), BM=64 (16 rows/wave), BN=128, BK=32
// A_F32: A is fp32 and converted to bf16 during staging.
// ---------------------------------------------------------------------------
template <bool OUT_BF16, bool A_F32>
__global__ __launch_bounds__(256) void gemm_bt_bf16(
    const void* __restrict__ Aptr, const unsigned short* __restrict__ Bt,
    void* __restrict__ C, int M, int N, int K) {
    constexpr int BM = 64, BN = 128, BK = 32, PAD = 8;
    constexpr int NT = BN / 16;                       // 8 n-tiles per wave
    __shared__ unsigned short As[BM][BK + PAD];       // 5 KB
    __shared__ unsigned short Bs[BN][BK + PAD];       // 10 KB
    const int tid  = threadIdx.x;
    const int wave = tid >> 6;
    const int lane = tid & 63;
    const int quad = lane >> 4;
    const int l16  = lane & 15;
    const int bm0 = blockIdx.x * BM;
    const int bn0 = blockIdx.y * BN;

    f32x4 acc[NT];
    #pragma unroll
    for (int j = 0; j < NT; ++j) acc[j] = (f32x4){0.f, 0.f, 0.f, 0.f};

    for (int kk = 0; kk < K; kk += BK) {
        {   // stage A: 64*32/8 = 256 chunks (1/thread)
            int row = tid >> 2, off = (tid & 3) * 8;
            if (A_F32) {
                const float* Af = (const float*)Aptr;
                const float4* src = (const float4*)&Af[(size_t)(bm0 + row) * K + kk + off];
                float4 a0 = src[0], a1 = src[1];
                uint4 p;
                p.x = pack2(a0.x, a0.y); p.y = pack2(a0.z, a0.w);
                p.z = pack2(a1.x, a1.y); p.w = pack2(a1.z, a1.w);
                *(uint4*)&As[row][off] = p;
            } else {
                const unsigned short* Ab = (const unsigned short*)Aptr;
                *(uint4*)&As[row][off] =
                    *(const uint4*)&Ab[(size_t)(bm0 + row) * K + kk + off];
            }
        }
        #pragma unroll
        for (int i = 0; i < 2; ++i) {   // stage Bt: 128*32/8 = 512 chunks
            int c2 = tid * 2 + i;
            int brow = c2 >> 2, boff = (c2 & 3) * 8;
            *(uint4*)&Bs[brow][boff] =
                *(const uint4*)&Bt[(size_t)(bn0 + brow) * K + kk + boff];
        }
        __syncthreads();
        bf16x8 af = *(const bf16x8*)&As[wave * 16 + l16][quad * 8];
        #pragma unroll
        for (int j = 0; j < NT; ++j) {
            bf16x8 bf = *(const bf16x8*)&Bs[j * 16 + l16][quad * 8];
            acc[j] = __builtin_amdgcn_mfma_f32_16x16x32_bf16(af, bf, acc[j], 0, 0, 0);
        }
        __syncthreads();
    }
    // C/D layout: col = lane&15, row = quad*4 + reg  (m89-verified)
    int row0 = bm0 + wave * 16 + quad * 4;
    #pragma unroll
    for (int j = 0; j < NT; ++j) {
        int col = bn0 + j * 16 + l16;
        #pragma unroll
        for (int r = 0; r < 4; ++r) {
            if (OUT_BF16)
                ((unsigned short*)C)[(size_t)(row0 + r) * N + col] = f2bs(acc[j][r]);
            else
                ((float*)C)[(size_t)(row0 + r) * N + col] = acc[j][r];
        }
    }
}

// ---------------------------------------------------------------------------
// Fused masked attention + output projection. Block = 256 thr = 4 waves,
// handles 16 sites; grid 768 (all blocks resident).
//  Attn : one FULL WAVE per site (4 sites/wave, sequential). Active rows from
//         a ballot bitmask (no LDS list). Row = 64 lanes x float4 (1 KB,
//         coalesced). 6-stage shuffle reduce -> every lane holds the 4 logits.
//         ONLINE softmax (defer-max THR=8, T13): running m,l,acc[4][4] in
//         regs -- hEV read exactly ONCE, no staging, no second pass.
//  evb  : acc/l -> bf16 -> LDS [16][1024], 16B-XOR-swizzled (T2:
//         byte ^= (site&7)<<4) so GEMM2's stride-2KB ds_read_b128 is ~2-way.
//  GEMM2: out(16x128) = evbS @ W3t^T, MFMA 16x16x32, K=1024; W3t (256 KB)
//         read per block from L2 (768 blocks -> 196 MB L2 ~ 6 us).
// ---------------------------------------------------------------------------
__global__ __launch_bounds__(256) void attn_out_fused(
    const float* __restrict__ hEV, const int* __restrict__ mask,
    const unsigned short* __restrict__ qt, const unsigned short* __restrict__ W3t,
    float* __restrict__ out) {
    __shared__ __align__(16) unsigned short evbS[16 * 1024];   // 32 KB
    const int tid  = threadIdx.x;
    const int lane = tid & 63;
    const int wv   = tid >> 6;
    const int s0   = blockIdx.x * 16;

    // ---- attention phase: wave wv handles sites wv*4 .. wv*4+3 ----
    for (int si = 0; si < 4; ++si) {
        const int site = wv * 4 + si;
        const int s = s0 + site;

        int mk = (lane < KNB) ? mask[(size_t)s * KNB + lane] : 0;
        unsigned long long bal = __ballot(mk > 0);
        unsigned mw = (unsigned)bal & 0x3FFFFFFFu;   // uniform across wave
        int na = __popc(mw);

        // q fragment: channels lane*4..+3, all 4 heads (bf16 -> f32)
        float qf[4][4];
        const unsigned short* qrow = qt + (size_t)s * 1024;
        #pragma unroll
        for (int h = 0; h < 4; ++h) {
            ushort4 u = *(const ushort4*)&qrow[h * 256 + lane * 4];
            qf[h][0] = bs2f(u.x); qf[h][1] = bs2f(u.y);
            qf[h][2] = bs2f(u.z); qf[h][3] = bs2f(u.w);
        }

        float mh[4], lh[4], acc[4][4];
        #pragma unroll
        for (int h = 0; h < 4; ++h) {
            mh[h] = -3.0e38f; lh[h] = 0.f;
            acc[h][0] = acc[h][1] = acc[h][2] = acc[h][3] = 0.f;
        }

        const float* base = hEV + (size_t)s * (KNB * CIN) + lane * 4;
        unsigned lmw = mw;
        float4 cur = {0,0,0,0}, nxt = {0,0,0,0};
        if (na > 0) {
            int k = __builtin_ctz(lmw); lmw &= lmw - 1;
            cur = *(const float4*)(base + (size_t)k * CIN);
        }
        for (int r = 0; r < na; ++r) {
            if (r + 1 < na) {                      // depth-2 pipeline
                int kn = __builtin_ctz(lmw); lmw &= lmw - 1;
                nxt = *(const float4*)(base + (size_t)kn * CIN);
            }
            float4 v = cur;
            float lg[4];
            #pragma unroll
            for (int h = 0; h < 4; ++h)
                lg[h] = v.x * qf[h][0] + v.y * qf[h][1]
                      + v.z * qf[h][2] + v.w * qf[h][3];
            #pragma unroll
            for (int mm = 1; mm < 64; mm <<= 1) {
                #pragma unroll
                for (int h = 0; h < 4; ++h) lg[h] += __shfl_xor(lg[h], mm, 64);
            }
            #pragma unroll
            for (int h = 0; h < 4; ++h) {
                float g = lg[h] * RSQRT_D;
                if (g > mh[h] + 8.f) {             // defer-max rescale (T13)
                    float sc = __expf(mh[h] - g);
                    lh[h] *= sc;
                    acc[h][0] *= sc; acc[h][1] *= sc;
                    acc[h][2] *= sc; acc[h][3] *= sc;
                    mh[h] = g;
                }
                float p = __expf(g - mh[h]);       // bounded by e^8
                lh[h] += p;
                acc[h][0] = fmaf(p, v.x, acc[h][0]);
                acc[h][1] = fmaf(p, v.y, acc[h][1]);
                acc[h][2] = fmaf(p, v.z, acc[h][2]);
                acc[h][3] = fmaf(p, v.w, acc[h][3]);
            }
            cur = nxt;
        }
        // evb[site][h*256 + lane*4 ..+3] = acc/l, bf16, swizzled 16B units
        const int swz = (site & 7) << 4;
        #pragma unroll
        for (int h = 0; h < 4; ++h) {
            float inv = (lh[h] > 0.f) ? 1.f / lh[h] : 0.f;
            unsigned p0 = pack2(acc[h][0] * inv, acc[h][1] * inv);
            unsigned p1 = pack2(acc[h][2] * inv, acc[h][3] * inv);
            int byte = (h * 512 + lane * 8) ^ swz;
            *(uint2*)((char*)evbS + site * 2048 + byte) = make_uint2(p0, p1);
        }
    }
    __syncthreads();

    // ---- GEMM2 phase: out(16x128) = evbS(16x1024) @ W3t^T ----
    const int quad = lane >> 4;
    const int l16  = lane & 15;            // site index for A-frag
    const int n0   = wv * 32;              // wave covers 2 n-tiles (32 cols)
    f32x4 oacc0 = (f32x4){0.f, 0.f, 0.f, 0.f};
    f32x4 oacc1 = (f32x4){0.f, 0.f, 0.f, 0.f};
    const int aswz = (l16 & 7) << 4;
    #pragma unroll 4
    for (int kk = 0; kk < 1024; kk += 32) {
        int abyte = ((kk + quad * 8) * 2) ^ aswz;
        bf16x8 af = *(const bf16x8*)((const char*)evbS + l16 * 2048 + abyte);
        bf16x8 b0 = *(const bf16x8*)&W3t[(size_t)(n0 + l16) * 1024 + kk + quad * 8];
        bf16x8 b1 = *(const bf16x8*)&W3t[(size_t)(n0 + 16 + l16) * 1024 + kk + quad * 8];
        oacc0 = __builtin_amdgcn_mfma_f32_16x16x32_bf16(af, b0, oacc0, 0, 0, 0);
        oacc1 = __builtin_amdgcn_mfma_f32_16x16x32_bf16(af, b1, oacc1, 0, 0, 0);
    }
    // C/D layout: col = l16 (n), row = quad*4 + r (site)
    int srow = s0 + quad * 4;
    #pragma unroll
    for (int r = 0; r < 4; ++r) {
        out[(size_t)(srow + r) * 128 + n0 + l16]      = oacc0[r];
        out[(size_t)(srow + r) * 128 + n0 + 16 + l16] = oacc1[r];
    }
}

// ---------------------------------------------------------------------------
extern "C" void kernel_launch(void* const* d_in, const int* in_sizes, int n_in,
                              void* d_out, int out_size, void* d_ws, size_t ws_size,
                              hipStream_t stream) {
    const float* hV   = (const float*)d_in[0];
    const float* hEV  = (const float*)d_in[1];
    const int*   mask = (const int*)d_in[2];
    const float* Wq   = (const float*)d_in[3];
    const float* Wk   = (const float*)d_in[4];
    const float* Wv   = (const float*)d_in[5];
    const float* Wo   = (const float*)d_in[6];
    float* out = (float*)d_out;

    unsigned short* ws = (unsigned short*)d_ws;   // element = 2 B
    unsigned short* Mt   = ws;                            // 1024*128
    unsigned short* W3t  = ws + 131072;                   // 128*1024
    unsigned short* qt   = ws + 262144;                   // 12288*1024
    size_t need = ((size_t)262144 + (size_t)SITES * 1024) * 2;
    if (ws_size < need) return;

    precompute_w<<<dim3(1024), dim3(256), 0, stream>>>(Wq, Wk, Wv, Wo, Mt, W3t);

    // qt (12288x1024, bf16) = bf16(hV) (12288x128) @ Mt^T
    gemm_bt_bf16<true, true><<<dim3(SITES / 64, 1024 / 128), dim3(256), 0, stream>>>(
        hV, Mt, qt, SITES, 1024, 128);

    // fused masked attention + output projection -> out (12288x128, fp32)
    attn_out_fused<<<dim3(SITES / 16), dim3(256), 0, stream>>>(
        hEV, mask, qt, W3t, out);
}